// Round 1
// baseline (15910.796 us; speedup 1.0000x reference)
//
#include <hip/hip_runtime.h>
#include <math.h>

#define NMAT   64
#define NPAD   65      // +1 pad: row access contiguous, col access bank=(j+p)%32 -> conflict-free
#define NPAIR  32
#define NTHR   256
#define SWEEPS 10

__global__ __launch_bounds__(NTHR)
void logeig_jacobi(const float* __restrict__ x, float* __restrict__ out) {
    __shared__ float A[NMAT][NPAD];
    __shared__ float V[NMAT][NPAD];
    __shared__ float rc[NPAIR];
    __shared__ float rs[NPAIR];
    __shared__ int   rp[NPAIR];
    __shared__ int   rq[NPAIR];
    __shared__ float logw[NMAT];

    const int tid = threadIdx.x;
    const size_t base = (size_t)blockIdx.x * (NMAT * NMAT);

    // Load A, init V = I
    for (int idx = tid; idx < NMAT * NMAT; idx += NTHR) {
        int i = idx >> 6, j = idx & 63;
        A[i][j] = x[base + idx];
        V[i][j] = (i == j) ? 1.0f : 0.0f;
    }
    __syncthreads();

    for (int sweep = 0; sweep < SWEEPS; ++sweep) {
        for (int r = 0; r < 63; ++r) {
            // --- phase 0: 32 lanes compute the 32 disjoint rotations (Brent-Luk) ---
            if (tid < NPAIR) {
                int p, q;
                if (tid == 0) {
                    p = 0;
                    q = 1 + r;                       // r in [0,63)
                } else {
                    p = 1 + (r + tid) % 63;
                    q = 1 + (r - tid + 63) % 63;
                }
                if (p > q) { int t = p; p = q; q = t; }
                float app = A[p][p];
                float aqq = A[q][q];
                float apq = A[p][q];
                float c = 1.0f, s = 0.0f;
                if (apq != 0.0f) {
                    float tau = (aqq - app) / (2.0f * apq);
                    float t   = copysignf(1.0f, tau) / (fabsf(tau) + sqrtf(1.0f + tau * tau));
                    c = 1.0f / sqrtf(1.0f + t * t);
                    s = t * c;
                }
                rc[tid] = c; rs[tid] = s; rp[tid] = p; rq[tid] = q;
            }
            __syncthreads();

            // --- phase 1: row update  A <- J^T A  (each wave: one pair, 64 cols) ---
            #pragma unroll
            for (int it = 0; it < 8; ++it) {
                int idx = tid + it * NTHR;
                int i = idx >> 6, j = idx & 63;
                int p = rp[i], q = rq[i];
                float c = rc[i], s = rs[i];
                float ap = A[p][j], aq = A[q][j];
                A[p][j] = c * ap - s * aq;
                A[q][j] = s * ap + c * aq;
            }
            __syncthreads();

            // --- phase 2: col update  A <- A J ;  V <- V J ---
            #pragma unroll
            for (int it = 0; it < 8; ++it) {
                int idx = tid + it * NTHR;
                int i = idx >> 6, j = idx & 63;
                int p = rp[i], q = rq[i];
                float c = rc[i], s = rs[i];
                float ap = A[j][p], aq = A[j][q];
                A[j][p] = c * ap - s * aq;
                A[j][q] = s * ap + c * aq;
                float vp = V[j][p], vq = V[j][q];
                V[j][p] = c * vp - s * vq;
                V[j][q] = s * vp + c * vq;
            }
            __syncthreads();
        }
    }

    // eigenvalues on the diagonal
    if (tid < NMAT) logw[tid] = logf(A[tid][tid]);
    __syncthreads();

    // W = V * diag(logw), stored into A
    for (int idx = tid; idx < NMAT * NMAT; idx += NTHR) {
        int i = idx >> 6, k = idx & 63;
        A[i][k] = V[i][k] * logw[k];
    }
    __syncthreads();

    // out[i][j] = sum_k W[i][k] * V[j][k]
    for (int idx = tid; idx < NMAT * NMAT; idx += NTHR) {
        int i = idx >> 6, j = idx & 63;
        float acc = 0.0f;
        #pragma unroll 8
        for (int k = 0; k < NMAT; ++k) acc += A[i][k] * V[j][k];
        out[base + idx] = acc;
    }
}

extern "C" void kernel_launch(void* const* d_in, const int* in_sizes, int n_in,
                              void* d_out, int out_size, void* d_ws, size_t ws_size,
                              hipStream_t stream) {
    const float* x = (const float*)d_in[0];
    float* out = (float*)d_out;
    int B = in_sizes[0] / (NMAT * NMAT);   // 8192
    logeig_jacobi<<<B, NTHR, 0, stream>>>(x, out);
}

// Round 2
// 10975.681 us; speedup vs baseline: 1.4496x; 1.4496x over previous
//
#include <hip/hip_runtime.h>
#include <math.h>

#define NMAT   64
#define APAD   65      // A padded: row access 2-way free, col access bank=(j+p)%32 free
#define NTHR   256
#define SWEEPS 8

__global__ __launch_bounds__(NTHR)
void logeig_jacobi(const float* __restrict__ x, float* __restrict__ out) {
    __shared__ float  A[NMAT][APAD];
    __shared__ float  Vt[NMAT][NMAT];   // V transposed; row ops only -> no pad needed
    __shared__ float4 prm[32];          // {c, s, p(asint), q(asint)} per pair
    __shared__ float  logw[NMAT];

    const int tid  = threadIdx.x;
    const int w    = tid >> 6;          // wave id 0..3
    const int lane = tid & 63;
    const size_t base = (size_t)blockIdx.x * (NMAT * NMAT);

    // ---- load A (float4 global reads), init Vt = I ----
    const float4* x4 = (const float4*)(x + base);
    for (int idx = tid; idx < NMAT * NMAT / 4; idx += NTHR) {
        int i  = idx >> 4;
        int j4 = (idx & 15) << 2;
        float4 v = x4[idx];
        A[i][j4 + 0] = v.x; A[i][j4 + 1] = v.y;
        A[i][j4 + 2] = v.z; A[i][j4 + 3] = v.w;
        Vt[i][j4 + 0] = (i == j4 + 0) ? 1.0f : 0.0f;
        Vt[i][j4 + 1] = (i == j4 + 1) ? 1.0f : 0.0f;
        Vt[i][j4 + 2] = (i == j4 + 2) ? 1.0f : 0.0f;
        Vt[i][j4 + 3] = (i == j4 + 3) ? 1.0f : 0.0f;
    }
    __syncthreads();

    for (int sweep = 0; sweep < SWEEPS; ++sweep) {
        for (int r = 0; r < 63; ++r) {
            // ---- phase 0: 32 lanes compute rotations (circle-method pairs) ----
            if (tid < 32) {
                int p, q;
                if (tid == 0) { p = 0; q = 1 + r; }
                else {
                    p = 1 + (r + tid) % 63;
                    q = 1 + (r - tid + 63) % 63;
                }
                if (p > q) { int t = p; p = q; q = t; }
                float app = A[p][p], aqq = A[q][q], apq = A[p][q];
                float c = 1.0f, s = 0.0f;
                if (apq != 0.0f) {
                    float tau = (aqq - app) / (2.0f * apq);
                    float t   = copysignf(1.0f, tau) / (fabsf(tau) + sqrtf(1.0f + tau * tau));
                    c = 1.0f / sqrtf(1.0f + t * t);
                    s = t * c;
                }
                float4 pk;
                pk.x = c; pk.y = s;
                pk.z = __int_as_float(p); pk.w = __int_as_float(q);
                prm[tid] = pk;
            }
            __syncthreads();

            // ---- phase 1: A <- J^T A (rows) and Vt <- J^T Vt, fused ----
            // wave w handles pairs 8w..8w+7; lane = column
            #pragma unroll
            for (int pp = 0; pp < 8; ++pp) {
                float4 pk = prm[(w << 3) | pp];
                float c = pk.x, s = pk.y;
                int p = __float_as_int(pk.z), q = __float_as_int(pk.w);
                float ap = A[p][lane], aq = A[q][lane];
                A[p][lane] = c * ap - s * aq;
                A[q][lane] = s * ap + c * aq;
                float vp = Vt[p][lane], vq = Vt[q][lane];
                Vt[p][lane] = c * vp - s * vq;
                Vt[q][lane] = s * vp + c * vq;
            }
            __syncthreads();

            // ---- phase 2: A <- A J (columns); lane = row ----
            #pragma unroll
            for (int pp = 0; pp < 8; ++pp) {
                float4 pk = prm[(w << 3) | pp];
                float c = pk.x, s = pk.y;
                int p = __float_as_int(pk.z), q = __float_as_int(pk.w);
                float ap = A[lane][p], aq = A[lane][q];
                A[lane][p] = c * ap - s * aq;
                A[lane][q] = s * ap + c * aq;
            }
            __syncthreads();
        }
    }

    // ---- eigenvalues on diag; W^T[k][i] = Vt[k][i]*logw[k] stored into A ----
    if (tid < NMAT) logw[tid] = logf(A[tid][tid]);
    __syncthreads();
    for (int idx = tid; idx < NMAT * NMAT; idx += NTHR) {
        int k = idx >> 6, i = idx & 63;
        A[k][i] = Vt[k][i] * logw[k];
    }
    __syncthreads();

    // ---- out[i][j] = sum_k Wt[k][i] * Vt[k][j] ----
    for (int ii = 0; ii < 16; ++ii) {
        int idx = tid + ii * NTHR;
        int i = idx >> 6, j = idx & 63;   // i is wave-uniform -> A[k][i] broadcasts
        float acc = 0.0f;
        #pragma unroll 8
        for (int k = 0; k < NMAT; ++k) acc += A[k][i] * Vt[k][j];
        out[base + idx] = acc;
    }
}

extern "C" void kernel_launch(void* const* d_in, const int* in_sizes, int n_in,
                              void* d_out, int out_size, void* d_ws, size_t ws_size,
                              hipStream_t stream) {
    const float* x = (const float*)d_in[0];
    float* out = (float*)d_out;
    int B = in_sizes[0] / (NMAT * NMAT);   // 8192
    logeig_jacobi<<<B, NTHR, 0, stream>>>(x, out);
}

// Round 3
// 6800.563 us; speedup vs baseline: 2.3396x; 1.6139x over previous
//
#include <hip/hip_runtime.h>
#include <math.h>

#define NTHR   256
#define SWEEPS 8

// Ring movement (round-robin / Brent-Luk): content of slot s moves to next(s).
// slot 0 fixed; even s -> s+2 (62 -> 63); odd s -> s-2 (1 -> 2).
__device__ __forceinline__ int ring_next_even(int s) {   // s even
    return (s == 0) ? 0 : ((s == 62) ? 63 : s + 2);
}
__device__ __forceinline__ int ring_next_odd(int s) {    // s odd
    return (s == 1) ? 2 : s - 2;
}

__global__ __launch_bounds__(NTHR)
void logeig_jacobi(const float* __restrict__ x, float* __restrict__ out) {
    __shared__ float A[64 * 64];
    __shared__ float Vt[64 * 64];
    __shared__ __align__(16) float2 prm[32];   // (c,s) per slot-pair k = (2k,2k+1)
    __shared__ float logw[64];

    const int tid = threadIdx.x;
    const int w   = tid >> 6;              // wave 0..3
    const int lan = tid & 63;
    const int J   = tid & 31;              // A-task column pair id
    const int bit = (lan >> 5) & 1;
    const int base = 8 * w + bit;          // A-task I = base + 2k, k=0..3
    const int b4  = (tid >> 4) & 1;
    const int cch = tid & 15;              // Vt float4 chunk

    // column destinations for A writes (thread-constant)
    const int cP  = 2 * J, cQ = 2 * J + 1;
    const int dPc = ring_next_even(cP);
    const int dQc = ring_next_odd(cQ);

    const size_t base_el = (size_t)blockIdx.x * 4096;

    // ---- load A (float4), init Vt = I ----
    {
        const float4* x4 = (const float4*)(x + base_el);
        for (int idx4 = tid; idx4 < 1024; idx4 += NTHR) {
            ((float4*)A)[idx4] = x4[idx4];
            int i = idx4 >> 4, j4 = idx4 & 15;
            float4 id;
            id.x = (4 * j4 + 0 == i) ? 1.0f : 0.0f;
            id.y = (4 * j4 + 1 == i) ? 1.0f : 0.0f;
            id.z = (4 * j4 + 2 == i) ? 1.0f : 0.0f;
            id.w = (4 * j4 + 3 == i) ? 1.0f : 0.0f;
            ((float4*)Vt)[idx4] = id;
        }
    }
    __syncthreads();

    for (int sweep = 0; sweep < SWEEPS; ++sweep) {
        for (int r = 0; r < 63; ++r) {
            // ---- stage P: rotation params for the 32 adjacent slot-pairs ----
            if (tid < 32) {
                int k = tid;
                float2 d0 = *(const float2*)&A[(2 * k) * 64 + 2 * k]; // app, apq
                float aqq = A[(2 * k + 1) * 64 + 2 * k + 1];
                float app = d0.x, apq = d0.y;
                float c = 1.0f, s = 0.0f;
                if (apq != 0.0f) {
                    float tau = (aqq - app) / (2.0f * apq);
                    float t   = copysignf(1.0f, tau) /
                                (fabsf(tau) + sqrtf(1.0f + tau * tau));
                    c = 1.0f / sqrtf(1.0f + t * t);
                    s = t * c;
                }
                prm[k] = make_float2(c, s);
            }

            // ---- fused reads of old A (2x2 blocks) and Vt (row chunks) ----
            float4 ablk[4];
            #pragma unroll
            for (int k = 0; k < 4; ++k) {
                int I = base + 2 * k;
                float2 top = *(const float2*)&A[(2 * I) * 64 + 2 * J];
                float2 bot = *(const float2*)&A[(2 * I + 1) * 64 + 2 * J];
                ablk[k] = make_float4(top.x, top.y, bot.x, bot.y);
            }
            float4 vtop[2], vbot[2];
            #pragma unroll
            for (int t = 0; t < 2; ++t) {
                int I = base + 2 * (2 * t + b4);
                vtop[t] = *(const float4*)&Vt[(2 * I) * 64 + 4 * cch];
                vbot[t] = *(const float4*)&Vt[(2 * I + 1) * 64 + 4 * cch];
            }
            __syncthreads();   // B1: all reads done; prm visible

            float2 pJ = prm[J];
            float2 pI[4];
            #pragma unroll
            for (int k = 0; k < 4; ++k) pI[k] = prm[base + 2 * k];

            // ---- rotate 2x2 blocks, write to ring-moved positions ----
            #pragma unroll
            for (int k = 0; k < 4; ++k) {
                float cI = pI[k].x, sI = pI[k].y;
                float cJ = pJ.x,   sJ = pJ.y;
                float m00 = ablk[k].x, m01 = ablk[k].y;
                float m10 = ablk[k].z, m11 = ablk[k].w;
                // left: G_I^T * M   (G = [[c,s],[-s,c]])
                float t00 = cI * m00 - sI * m10, t01 = cI * m01 - sI * m11;
                float t10 = sI * m00 + cI * m10, t11 = sI * m01 + cI * m11;
                // right: (.) * G_J
                float n00 = cJ * t00 - sJ * t01, n01 = sJ * t00 + cJ * t01;
                float n10 = cJ * t10 - sJ * t11, n11 = sJ * t10 + cJ * t11;
                int I  = base + 2 * k;
                int dPr = ring_next_even(2 * I);
                int dQr = ring_next_odd(2 * I + 1);
                A[dPr * 64 + dPc] = n00;
                A[dPr * 64 + dQc] = n01;
                A[dQr * 64 + dPc] = n10;
                A[dQr * 64 + dQc] = n11;
            }

            // ---- rotate Vt rows (left only), write to ring-moved rows ----
            #pragma unroll
            for (int t = 0; t < 2; ++t) {
                int k  = 2 * t + b4;
                float cI = pI[k].x, sI = pI[k].y;
                int I  = base + 2 * k;
                int dPr = ring_next_even(2 * I);
                int dQr = ring_next_odd(2 * I + 1);
                float4 v0 = vtop[t], v1 = vbot[t];
                float4 n0, n1;
                n0.x = cI * v0.x - sI * v1.x;  n1.x = sI * v0.x + cI * v1.x;
                n0.y = cI * v0.y - sI * v1.y;  n1.y = sI * v0.y + cI * v1.y;
                n0.z = cI * v0.z - sI * v1.z;  n1.z = sI * v0.z + cI * v1.z;
                n0.w = cI * v0.w - sI * v1.w;  n1.w = sI * v0.w + cI * v1.w;
                *(float4*)&Vt[dPr * 64 + 4 * cch] = n0;
                *(float4*)&Vt[dQr * 64 + 4 * cch] = n1;
            }
            __syncthreads();   // B2: writes done -> next round
        }
    }

    // ---- epilogue: out = Vt^T diag(log diag A) Vt ----
    if (tid < 64) logw[tid] = logf(A[tid * 64 + tid]);
    __syncthreads();

    // W[s][*] = Vt[s][*] * logw[s], stored into A
    for (int idx4 = tid; idx4 < 1024; idx4 += NTHR) {
        int k = idx4 >> 4;
        float lw = logw[k];
        float4 v = ((float4*)Vt)[idx4];
        v.x *= lw; v.y *= lw; v.z *= lw; v.w *= lw;
        ((float4*)A)[idx4] = v;
    }
    __syncthreads();

    // out[i][j] = sum_s W[s][i] * Vt[s][j]   (float4 over j)
    float4* out4 = (float4*)(out + base_el);
    #pragma unroll
    for (int ii = 0; ii < 4; ++ii) {
        int idx4 = tid + ii * NTHR;
        int i = idx4 >> 4, j4 = idx4 & 15;
        float4 acc = make_float4(0.0f, 0.0f, 0.0f, 0.0f);
        #pragma unroll 8
        for (int k = 0; k < 64; ++k) {
            float a = A[k * 64 + i];
            float4 vv = ((float4*)Vt)[k * 16 + j4];
            acc.x += a * vv.x; acc.y += a * vv.y;
            acc.z += a * vv.z; acc.w += a * vv.w;
        }
        out4[idx4] = acc;
    }
}

extern "C" void kernel_launch(void* const* d_in, const int* in_sizes, int n_in,
                              void* d_out, int out_size, void* d_ws, size_t ws_size,
                              hipStream_t stream) {
    const float* x = (const float*)d_in[0];
    float* o = (float*)d_out;
    int B = in_sizes[0] / 4096;   // 8192
    logeig_jacobi<<<B, NTHR, 0, stream>>>(x, o);
}

// Round 5
// 5987.773 us; speedup vs baseline: 2.6572x; 1.1357x over previous
//
#include <hip/hip_runtime.h>
#include <math.h>

#define NTHR   256
#define SWEEPS 7

// Ring movement (round-robin / Brent-Luk): content of slot s moves to next(s).
// slot 0 fixed; even s -> s+2 (62 -> 63); odd s -> s-2 (1 -> 2).
__device__ __forceinline__ int ring_next_even(int s) {   // s even
    return (s == 0) ? 0 : ((s == 62) ? 63 : s + 2);
}
__device__ __forceinline__ int ring_next_odd(int s) {    // s odd
    return (s == 1) ? 2 : s - 2;
}
// Split-parity column position: even cols -> 0..31, odd cols -> 32..63.
// Makes the 32 same-parity column accesses of one instr hit 32 distinct banks.
__device__ __forceinline__ int cpos(int c) {
    return (c >> 1) + ((c & 1) << 5);
}

__global__ __launch_bounds__(NTHR)
void logeig_jacobi(const float* __restrict__ x, float* __restrict__ out) {
    __shared__ float A[64 * 64];    // rows x split-parity column positions
    __shared__ float Vt[64 * 64];   // plain row-major (rows move, cols never)
    __shared__ __align__(16) float2 prm[32];
    __shared__ float logw[64];

    const int tid = threadIdx.x;
    const int w   = tid >> 6;
    const int lan = tid & 63;
    const int J   = tid & 31;              // column-pair id
    const int bit = (lan >> 5) & 1;
    const int base = 8 * w + bit;          // row-pair I = base + 2k
    const int b4  = (tid >> 4) & 1;
    const int cch = tid & 15;              // Vt float4 chunk

    // thread-constant A write column positions (after ring move)
    const int wpP = cpos(ring_next_even(2 * J));
    const int wpQ = cpos(ring_next_odd(2 * J + 1));

    const size_t base_el = (size_t)blockIdx.x * 4096;

    // ---- load A into split-parity layout (float4 -> two float2), Vt = I ----
    {
        const float4* x4 = (const float4*)(x + base_el);
        for (int idx4 = tid; idx4 < 1024; idx4 += NTHR) {
            int i = idx4 >> 4, t = idx4 & 15;      // cols 4t..4t+3
            float4 v = x4[idx4];
            // evens 4t,4t+2 -> pos 2t,2t+1 ; odds -> pos 32+2t, 32+2t+1
            *(float2*)&A[i * 64 + 2 * t]      = make_float2(v.x, v.z);
            *(float2*)&A[i * 64 + 32 + 2 * t] = make_float2(v.y, v.w);
            float4 id;
            id.x = (4 * t + 0 == i) ? 1.0f : 0.0f;
            id.y = (4 * t + 1 == i) ? 1.0f : 0.0f;
            id.z = (4 * t + 2 == i) ? 1.0f : 0.0f;
            id.w = (4 * t + 3 == i) ? 1.0f : 0.0f;
            ((float4*)Vt)[idx4] = id;
        }
    }
    __syncthreads();

    for (int sweep = 0; sweep < SWEEPS; ++sweep) {
        for (int r = 0; r < 63; ++r) {
            // ---- rotation params for the 32 adjacent slot pairs ----
            if (tid < 32) {
                int k = tid;
                float app = A[(2 * k) * 64 + k];            // pos(2k)   = k
                float apq = A[(2 * k) * 64 + k + 32];       // pos(2k+1) = k+32
                float aqq = A[(2 * k + 1) * 64 + k + 32];
                float c = 1.0f, s = 0.0f;
                if (apq != 0.0f) {
                    float tau = (aqq - app) / (2.0f * apq);
                    float t   = copysignf(1.0f, tau) /
                                (fabsf(tau) + sqrtf(1.0f + tau * tau));
                    c = 1.0f / sqrtf(1.0f + t * t);
                    s = t * c;
                }
                prm[k] = make_float2(c, s);
            }

            // ---- read old A 2x2 blocks (conflict-free b32 pairs) and Vt ----
            float4 ablk[4];
            #pragma unroll
            for (int k = 0; k < 4; ++k) {
                int r0 = (2 * (base + 2 * k)) * 64;
                int r1 = r0 + 64;
                ablk[k] = make_float4(A[r0 + J], A[r0 + J + 32],
                                      A[r1 + J], A[r1 + J + 32]);
            }
            float4 vtop[2], vbot[2];
            #pragma unroll
            for (int t = 0; t < 2; ++t) {
                int I = base + 2 * (2 * t + b4);
                vtop[t] = *(const float4*)&Vt[(2 * I) * 64 + 4 * cch];
                vbot[t] = *(const float4*)&Vt[(2 * I + 1) * 64 + 4 * cch];
            }
            __syncthreads();   // B1: all reads done; prm visible

            float2 pJ = prm[J];
            float2 pI[4];
            #pragma unroll
            for (int k = 0; k < 4; ++k) pI[k] = prm[base + 2 * k];

            // ---- rotate 2x2 blocks, write to ring-moved positions ----
            #pragma unroll
            for (int k = 0; k < 4; ++k) {
                float cI = pI[k].x, sI = pI[k].y;
                float cJ = pJ.x,   sJ = pJ.y;
                float m00 = ablk[k].x, m01 = ablk[k].y;
                float m10 = ablk[k].z, m11 = ablk[k].w;
                float t00 = cI * m00 - sI * m10, t01 = cI * m01 - sI * m11;
                float t10 = sI * m00 + cI * m10, t11 = sI * m01 + cI * m11;
                float n00 = cJ * t00 - sJ * t01, n01 = sJ * t00 + cJ * t01;
                float n10 = cJ * t10 - sJ * t11, n11 = sJ * t10 + cJ * t11;
                int I  = base + 2 * k;
                int dPr = ring_next_even(2 * I) * 64;
                int dQr = ring_next_odd(2 * I + 1) * 64;
                A[dPr + wpP] = n00;
                A[dPr + wpQ] = n01;
                A[dQr + wpP] = n10;
                A[dQr + wpQ] = n11;
            }

            // ---- rotate Vt rows, write to ring-moved rows ----
            #pragma unroll
            for (int t = 0; t < 2; ++t) {
                int k  = 2 * t + b4;
                float cI = pI[k].x, sI = pI[k].y;
                int I  = base + 2 * k;
                int dPr = ring_next_even(2 * I);
                int dQr = ring_next_odd(2 * I + 1);
                float4 v0 = vtop[t], v1 = vbot[t];
                float4 n0, n1;
                n0.x = cI * v0.x - sI * v1.x;  n1.x = sI * v0.x + cI * v1.x;
                n0.y = cI * v0.y - sI * v1.y;  n1.y = sI * v0.y + cI * v1.y;
                n0.z = cI * v0.z - sI * v1.z;  n1.z = sI * v0.z + cI * v1.z;
                n0.w = cI * v0.w - sI * v1.w;  n1.w = sI * v0.w + cI * v1.w;
                *(float4*)&Vt[dPr * 64 + 4 * cch] = n0;
                *(float4*)&Vt[dQr * 64 + 4 * cch] = n1;
            }
            __syncthreads();   // B2: writes done -> next round
        }
    }

    // ---- epilogue: out = Vt^T diag(log diag A) Vt ----
    if (tid < 64) {
        int p = (tid >> 1) + ((tid & 1) << 5);   // cpos(tid)
        logw[tid] = logf(A[tid * 64 + p]);
    }
    __syncthreads();

    // W[s][*] = Vt[s][*] * logw[s]  -> reuse A (plain layout now)
    for (int idx4 = tid; idx4 < 1024; idx4 += NTHR) {
        int k = idx4 >> 4;
        float lw = logw[k];
        float4 v = ((float4*)Vt)[idx4];
        v.x *= lw; v.y *= lw; v.z *= lw; v.w *= lw;
        ((float4*)A)[idx4] = v;
    }
    __syncthreads();

    // out[i][j] = sum_s W[s][i] * Vt[s][j]
    float4* out4 = (float4*)(out + base_el);
    #pragma unroll
    for (int ii = 0; ii < 4; ++ii) {
        int idx4 = tid + ii * NTHR;
        int i = idx4 >> 4, j4 = idx4 & 15;
        float4 acc = make_float4(0.0f, 0.0f, 0.0f, 0.0f);
        #pragma unroll 8
        for (int k = 0; k < 64; ++k) {
            float a = A[k * 64 + i];
            float4 vv = ((float4*)Vt)[k * 16 + j4];
            acc.x += a * vv.x; acc.y += a * vv.y;
            acc.z += a * vv.z; acc.w += a * vv.w;
        }
        out4[idx4] = acc;
    }
}

extern "C" void kernel_launch(void* const* d_in, const int* in_sizes, int n_in,
                              void* d_out, int out_size, void* d_ws, size_t ws_size,
                              hipStream_t stream) {
    const float* x = (const float*)d_in[0];
    float* o = (float*)d_out;
    int B = in_sizes[0] / 4096;   // 8192
    logeig_jacobi<<<B, NTHR, 0, stream>>>(x, o);
}